// Round 2
// baseline (13298.535 us; speedup 1.0000x reference)
//
#include <hip/hip_runtime.h>
#include <stdint.h>

#define BB 128
#define TT 1024
#define II 256
#define HH 256
#define G4 1024
#define YD 16   // y1 inter-layer ring depth (power of 2)

typedef __attribute__((ext_vector_type(8))) short short8;
typedef __attribute__((ext_vector_type(4))) float float4v;
typedef unsigned long long ull;

union S8U { short8 s; unsigned u[4]; ull l[2]; };

__device__ __forceinline__ unsigned short f2bf(float f) {
  union { float f; unsigned u; } v; v.f = f;
  unsigned u = v.u + 0x7FFFu + ((v.u >> 16) & 1u);  // RNE
  return (unsigned short)(u >> 16);
}
__device__ __forceinline__ unsigned cvtpk(float lo, float hi) {
  unsigned r;
  asm("v_cvt_pk_bf16_f32 %0, %1, %2" : "=v"(r) : "v"(lo), "v"(hi));
  return r;
}
__device__ __forceinline__ float sigm(float x) { return 1.f / (1.f + __expf(-x)); }
__device__ __forceinline__ float tanh_(float x) { return 2.f / (1.f + __expf(-2.f * x)) - 1.f; }

#define ALOAD64(p) __hip_atomic_load((const ull*)(p), __ATOMIC_RELAXED, __HIP_MEMORY_SCOPE_AGENT)
#define ASTORE16(p, v) __hip_atomic_store((unsigned short*)(p), (unsigned short)(v), __ATOMIC_RELAXED, __HIP_MEMORY_SCOPE_AGENT)

// 64 persistent blocks = [layer(2)] x [batch-group(4) of 32 rows] x [gate-slice(8) of 32 j].
// Waves are fully independent in the t-loop (per-wave flags, no __syncthreads):
// A = weights (M=gate rows, register-resident), B = [x_t | h_{t-1}] (N=batch),
// so each thread's 4 acc regs are (i,f,g,o) of one (b,j) -> elementwise in registers.
// All cross-block traffic (h, y1, flags) is relaxed agent-scope atomics (sc1, LLC-coherent);
// no cache-wide fences anywhere.
__global__ __launch_bounds__(256, 1) void vlstm(
    const float* __restrict__ x, const float* __restrict__ W_ih,
    const float* __restrict__ W_hh, const float* __restrict__ b_ih,
    const float* __restrict__ b_hh, const float* __restrict__ masks,
    float* __restrict__ out, int* __restrict__ flags,
    unsigned short* __restrict__ hstate, unsigned short* __restrict__ y1ring)
{
  const int tid = threadIdx.x, bid = blockIdx.x;
  const int layer = bid >> 5, bg = (bid >> 3) & 3, gs = bid & 7;
  const int bbase = bg * 32, jbase = gs * 32;

  __shared__ unsigned short Wlds[128][520];  // 128 gate rows x (256 ih | 256 hh), +8 pad
  __shared__ float bias_sh[128];

  // ---- one-time staging: weight slice -> LDS (row n = jl*4+q -> global row q*H + jbase + jl)
  const float* Wih_l = W_ih + (size_t)layer * G4 * II;
  const float* Whh_l = W_hh + (size_t)layer * G4 * HH;
  for (int e = tid; e < 128 * 512; e += 256) {
    int n = e >> 9, c = e & 511;
    int r = (n & 3) * HH + jbase + (n >> 2);
    float w = (c < 256) ? Wih_l[(size_t)r * II + c] : Whh_l[(size_t)r * HH + (c - 256)];
    Wlds[n][c] = f2bf(w);
  }
  if (tid < 128) {
    int r = (tid & 3) * HH + jbase + (tid >> 2);
    bias_sh[tid] = b_ih[layer * G4 + r] + b_hh[layer * G4 + r];
  }
  __syncthreads();

  const int wv = tid >> 6, lane = tid & 63, lr = lane & 15, lg = lane >> 4;

  // ---- weight A-fragments -> registers, constant over time (2 M-tiles x 16 k-tiles)
  short8 af[2][16];
  #pragma unroll
  for (int mtr = 0; mtr < 2; ++mtr)
    #pragma unroll
    for (int kt = 0; kt < 16; ++kt)
      af[mtr][kt] = *(const short8*)&Wlds[(wv * 2 + mtr) * 16 + lr][kt * 32 + lg * 8];

  // ---- per-thread cell state / masks / bias (items: [mtr][nt] -> j = jbase+(wv*2+mtr)*4+lg, b = bbase+nt*16+lr)
  float bja[2][4], cst[2][2], mo[2][2], mh[2][2], mc[2][2];
  #pragma unroll
  for (int mtr = 0; mtr < 2; ++mtr) {
    int jl = (wv * 2 + mtr) * 4 + lg;
    #pragma unroll
    for (int q = 0; q < 4; ++q) bja[mtr][q] = bias_sh[jl * 4 + q];
    int j = jbase + jl;
    const float* mk = masks + (size_t)layer * 3 * BB * HH;
    #pragma unroll
    for (int nt = 0; nt < 2; ++nt) {
      int b = bbase + nt * 16 + lr;
      mo[mtr][nt] = mk[(size_t)b * HH + j];
      mh[mtr][nt] = mk[(size_t)BB * HH + (size_t)b * HH + j];
      mc[mtr][nt] = mk[(size_t)2 * BB * HH + (size_t)b * HH + j];
      cst[mtr][nt] = 0.f;
    }
  }

  int* myf = flags + (layer * 4 + bg) * 32;        // this group's 32 per-wave flags
  int* otf = flags + ((1 ^ layer) * 4 + bg) * 32;  // other layer, same bg
  const int w32 = gs * 4 + wv;
  int* pollp = (lane < 32) ? (myf + lane) : (otf + (lane - 32));
  const int thradd = (lane < 32) ? 0 : (layer ? 1 : -(YD - 1));
  unsigned short* hs_l = hstate + (size_t)layer * 2 * BB * HH;

  for (int t = 0; t < TT; ++t) {
    S8U blo[2][8], bhi[2][8];

    // ---- x prefetch + bf16 convert BEFORE poll (no flag dependency; latency hides under wait)
    if (layer == 0) {
      #pragma unroll
      for (int nt = 0; nt < 2; ++nt) {
        int b = bbase + nt * 16 + lr;
        const float* xp = x + ((size_t)b * TT + t) * II + lg * 8;
        #pragma unroll
        for (int kt = 0; kt < 8; ++kt) {
          float4v v0 = *(const float4v*)(xp + kt * 32);
          float4v v1 = *(const float4v*)(xp + kt * 32 + 4);
          blo[nt][kt].u[0] = cvtpk(v0[0], v0[1]);
          blo[nt][kt].u[1] = cvtpk(v0[2], v0[3]);
          blo[nt][kt].u[2] = cvtpk(v1[0], v1[1]);
          blo[nt][kt].u[3] = cvtpk(v1[2], v1[3]);
        }
      }
    }

    // ---- poll: lanes 0..31 own-layer flags >= t; lanes 32..63 other-layer
    //      (layer1: y1_t ready -> >= t+1; layer0: ring slot free -> >= t-15)
    {
      const int thr = t + thradd;
      int it = 0;
      for (;;) {
        int v = __hip_atomic_load(pollp, __ATOMIC_RELAXED, __HIP_MEMORY_SCOPE_AGENT);
        if (__all(v >= thr)) break;
        if (++it > (1 << 22)) break;  // safety: never hang the harness
      }
      __atomic_signal_fence(__ATOMIC_ACQUIRE);
    }

    // ---- flag-gated inputs: y1 (layer1 only) and h_{t-1}, coherent 8B atomic loads
    if (layer == 1) {
      #pragma unroll
      for (int nt = 0; nt < 2; ++nt) {
        int b = bbase + nt * 16 + lr;
        const unsigned short* yp = y1ring + ((size_t)(t & (YD - 1)) * BB + b) * HH + lg * 8;
        #pragma unroll
        for (int kt = 0; kt < 8; ++kt) {
          blo[nt][kt].l[0] = ALOAD64(yp + kt * 32);
          blo[nt][kt].l[1] = ALOAD64(yp + kt * 32 + 4);
        }
      }
    }
    const unsigned short* hread = hs_l + (size_t)((t + 1) & 1) * BB * HH;
    #pragma unroll
    for (int nt = 0; nt < 2; ++nt) {
      int b = bbase + nt * 16 + lr;
      const unsigned short* hp = hread + (size_t)b * HH + lg * 8;
      #pragma unroll
      for (int kt = 0; kt < 8; ++kt) {
        bhi[nt][kt].l[0] = ALOAD64(hp + kt * 32);
        bhi[nt][kt].l[1] = ALOAD64(hp + kt * 32 + 4);
      }
    }

    // ---- MFMA: D[m=gate_row][n=batch]; x|y half first (h loads still in flight)
    float4v acc[2][2] = {};
    #pragma unroll
    for (int kt = 0; kt < 8; ++kt)
      #pragma unroll
      for (int nt = 0; nt < 2; ++nt)
        #pragma unroll
        for (int mtr = 0; mtr < 2; ++mtr)
          acc[mtr][nt] = __builtin_amdgcn_mfma_f32_16x16x32_bf16(
              af[mtr][kt], blo[nt][kt].s, acc[mtr][nt], 0, 0, 0);
    #pragma unroll
    for (int kt = 0; kt < 8; ++kt)
      #pragma unroll
      for (int nt = 0; nt < 2; ++nt)
        #pragma unroll
        for (int mtr = 0; mtr < 2; ++mtr)
          acc[mtr][nt] = __builtin_amdgcn_mfma_f32_16x16x32_bf16(
              af[mtr][8 + kt], bhi[nt][kt].s, acc[mtr][nt], 0, 0, 0);

    // ---- elementwise cell, fully in registers (acc regs 0..3 = i,f,g,o of one (b,j))
    unsigned short* hw = hs_l + (size_t)(t & 1) * BB * HH;
    #pragma unroll
    for (int mtr = 0; mtr < 2; ++mtr)
      #pragma unroll
      for (int nt = 0; nt < 2; ++nt) {
        float gi = sigm(acc[mtr][nt][0] + bja[mtr][0]);
        float gf = sigm(acc[mtr][nt][1] + bja[mtr][1]);
        float gg = tanh_(acc[mtr][nt][2] + bja[mtr][2]);
        float go = sigm(acc[mtr][nt][3] + bja[mtr][3]);
        float c2 = gf * cst[mtr][nt] + gi * gg;
        float h2 = go * tanh_(c2);
        cst[mtr][nt] = c2 * mc[mtr][nt];
        int b = bbase + nt * 16 + lr, j = jbase + (wv * 2 + mtr) * 4 + lg;
        ASTORE16(hw + (size_t)b * HH + j, f2bf(h2 * mh[mtr][nt]));
        if (layer == 0)
          ASTORE16(y1ring + ((size_t)(t & (YD - 1)) * BB + b) * HH + j, f2bf(h2 * mo[mtr][nt]));
        else
          out[((size_t)b * TT + t) * HH + j] = h2 * mo[mtr][nt];
      }

    // ---- publish: drain all stores to LLC, then bump this wave's flag (relaxed, sc1)
    __atomic_signal_fence(__ATOMIC_RELEASE);
    __builtin_amdgcn_s_waitcnt(0);
    __hip_atomic_store(myf + w32, t + 1, __ATOMIC_RELAXED, __HIP_MEMORY_SCOPE_AGENT);
  }
}

extern "C" void kernel_launch(void* const* d_in, const int* in_sizes, int n_in,
                              void* d_out, int out_size, void* d_ws, size_t ws_size,
                              hipStream_t stream) {
  const float* x     = (const float*)d_in[0];
  const float* W_ih  = (const float*)d_in[1];
  const float* W_hh  = (const float*)d_in[2];
  const float* b_ih  = (const float*)d_in[3];
  const float* b_hh  = (const float*)d_in[4];
  const float* masks = (const float*)d_in[5];
  float* out = (float*)d_out;

  const size_t FLAG_BYTES = (size_t)2 * 4 * 32 * sizeof(int);                 //   1 KB
  const size_t HS_BYTES   = (size_t)2 * 2 * BB * HH * sizeof(unsigned short); // 256 KB
  int* flags = (int*)d_ws;
  unsigned short* hstate = (unsigned short*)((char*)d_ws + FLAG_BYTES);
  unsigned short* y1ring = (unsigned short*)((char*)d_ws + FLAG_BYTES + HS_BYTES);

  hipMemsetAsync(d_ws, 0, FLAG_BYTES + HS_BYTES, stream);  // flags=0, h(t=-1)=0
  vlstm<<<dim3(64), dim3(256), 0, stream>>>(x, W_ih, W_hh, b_ih, b_hh, masks,
                                            out, flags, hstate, y1ring);
}